// Round 1
// baseline (209.550 us; speedup 1.0000x reference)
//
#include <hip/hip_runtime.h>
#include <math.h>

// Problem constants (match the JAX reference)
constexpr int Bn = 8;       // batch
constexpr int An = 120000;  // anchors
constexpr int Cn = 80;      // classes
constexpr int Mn = 32;      // max GT boxes
constexpr int APB = 256;    // anchors per block

// Per-image accumulators in d_ws: [b][0]=cls_sum, [b][1]=reg_sum, [b][2]=pos_count
__global__ __launch_bounds__(256) void focal_main(
    const float* __restrict__ cls,   // [B,A,C]
    const float* __restrict__ regr,  // [B,A,4]
    const float* __restrict__ anch,  // [1,A,4]
    const float* __restrict__ ann,   // [B,M,5]
    float* __restrict__ acc)         // [B*3]
{
    const int b  = blockIdx.y;
    const int a0 = blockIdx.x * APB;
    const int t  = threadIdx.x;

    __shared__ float s_ann[Mn * 5];
    __shared__ int   s_status[APB];  // class idx if pos; -1 neg; -2 ignore/out-of-range

    if (t < Mn * 5) s_ann[t] = ann[b * Mn * 5 + t];
    __syncthreads();

    float r_sum = 0.0f;
    float p_cnt = 0.0f;

    // ---- Phase A: per-anchor IoU matching + regression loss (1 anchor/thread)
    {
        const int a = a0 + t;
        int status = -2;
        if (a < An) {
            const float4 ab = *reinterpret_cast<const float4*>(anch + (size_t)a * 4);
            const float aw = ab.z - ab.x, ah = ab.w - ab.y;
            const float aarea = aw * ah;
            float best = -INFINITY;
            int   arg  = 0;
            #pragma unroll
            for (int m = 0; m < Mn; ++m) {
                const float bx1 = s_ann[m * 5 + 0], by1 = s_ann[m * 5 + 1];
                const float bx2 = s_ann[m * 5 + 2], by2 = s_ann[m * 5 + 3];
                float iw = fminf(ab.z, bx2) - fmaxf(ab.x, bx1);
                float ih = fminf(ab.w, by2) - fmaxf(ab.y, by1);
                iw = fmaxf(iw, 0.0f);
                ih = fmaxf(ih, 0.0f);
                const float inter = iw * ih;
                const float ua = fmaxf(aarea + (bx2 - bx1) * (by2 - by1) - inter, 1e-8f);
                const float v  = (s_ann[m * 5 + 4] != -1.0f) ? (inter / ua) : -1.0f;
                if (v > best) { best = v; arg = m; }  // strict > == first-max (jnp.argmax)
            }
            if (best >= 0.5f) {
                status = (int)s_ann[arg * 5 + 4];
                p_cnt  = 1.0f;
                const float gx1 = s_ann[arg * 5 + 0], gy1 = s_ann[arg * 5 + 1];
                const float gx2 = s_ann[arg * 5 + 2], gy2 = s_ann[arg * 5 + 3];
                float gw = gx2 - gx1, gh = gy2 - gy1;
                const float gcx = gx1 + 0.5f * gw, gcy = gy1 + 0.5f * gh; // ctr from UNclamped wh
                gw = fmaxf(gw, 1.0f);
                gh = fmaxf(gh, 1.0f);
                const float acx = ab.x + 0.5f * aw, acy = ab.y + 0.5f * ah;
                const float4 rg = *reinterpret_cast<const float4*>(regr + ((size_t)b * An + a) * 4);
                const float t0 = (gcx - acx) / aw * 10.0f;   // /0.1
                const float t1 = (gcy - acy) / ah * 10.0f;
                const float t2 = __logf(gw / aw) * 5.0f;     // /0.2
                const float t3 = __logf(gh / ah) * 5.0f;
                float d;
                d = fabsf(t0 - rg.x); r_sum += (d <= (1.0f / 9.0f)) ? 4.5f * d * d : d - (0.5f / 9.0f);
                d = fabsf(t1 - rg.y); r_sum += (d <= (1.0f / 9.0f)) ? 4.5f * d * d : d - (0.5f / 9.0f);
                d = fabsf(t2 - rg.z); r_sum += (d <= (1.0f / 9.0f)) ? 4.5f * d * d : d - (0.5f / 9.0f);
                d = fabsf(t3 - rg.w); r_sum += (d <= (1.0f / 9.0f)) ? 4.5f * d * d : d - (0.5f / 9.0f);
            } else if (best < 0.4f) {
                status = -1;  // negative
            }                 // else ignore band [0.4, 0.5)
        }
        s_status[t] = status;
    }
    __syncthreads();

    // ---- Phase B: focal classification loss (16 threads/anchor, coalesced rows)
    float c_sum = 0.0f;
    {
        const int lane_c = t & 15;
        const int arow   = t >> 4;  // 0..15
        const float* imgbase = cls + (size_t)b * An * Cn;
        for (int it = 0; it < APB / 16; ++it) {
            const int al = it * 16 + arow;
            const int status = s_status[al];
            if (status == -2) continue;  // ignore band contributes 0 -> skip the row read
            const float* row = imgbase + (size_t)(a0 + al) * Cn;
            #pragma unroll
            for (int j = 0; j < 5; ++j) {
                const int c = j * 16 + lane_c;
                float p = row[c];
                p = fminf(fmaxf(p, 1e-4f), 1.0f - 1e-4f);
                float term;
                if (c == status) {  // target == 1
                    const float om = 1.0f - p;
                    term = 0.25f * om * om * (-__logf(p));
                } else {            // target == 0
                    term = 0.75f * p * p * (-__logf(1.0f - p));
                }
                c_sum += term;
            }
        }
    }

    // ---- Block reduction + per-image atomics
    #pragma unroll
    for (int off = 32; off > 0; off >>= 1) {
        c_sum += __shfl_down(c_sum, off);
        r_sum += __shfl_down(r_sum, off);
        p_cnt += __shfl_down(p_cnt, off);
    }
    __shared__ float s_c[4], s_r[4], s_p[4];
    const int wv = t >> 6;
    if ((t & 63) == 0) { s_c[wv] = c_sum; s_r[wv] = r_sum; s_p[wv] = p_cnt; }
    __syncthreads();
    if (t == 0) {
        atomicAdd(&acc[b * 3 + 0], s_c[0] + s_c[1] + s_c[2] + s_c[3]);
        atomicAdd(&acc[b * 3 + 1], s_r[0] + s_r[1] + s_r[2] + s_r[3]);
        atomicAdd(&acc[b * 3 + 2], s_p[0] + s_p[1] + s_p[2] + s_p[3]);
    }
}

__global__ void focal_final(const float* __restrict__ acc,
                            const float* __restrict__ ann,
                            float* __restrict__ out)
{
    if (threadIdx.x == 0 && blockIdx.x == 0) {
        float cm = 0.0f, rm = 0.0f;
        for (int b = 0; b < Bn; ++b) {
            int nv = 0;
            for (int m = 0; m < Mn; ++m)
                nv += (ann[b * Mn * 5 + m * 5 + 4] != -1.0f) ? 1 : 0;
            const float np  = acc[b * 3 + 2];
            const float npc = fmaxf(np, 1.0f);
            float cl = acc[b * 3 + 0] / npc;
            float rl = (np > 0.0f) ? acc[b * 3 + 1] / (npc * 4.0f) : 0.0f;
            if (nv == 0) { cl = 0.0f; rl = 0.0f; }
            cm += cl;
            rm += rl;
        }
        out[0] = cm / (float)Bn;
        out[1] = rm / (float)Bn;
    }
}

extern "C" void kernel_launch(void* const* d_in, const int* in_sizes, int n_in,
                              void* d_out, int out_size, void* d_ws, size_t ws_size,
                              hipStream_t stream) {
    const float* cls  = (const float*)d_in[0];
    const float* regr = (const float*)d_in[1];
    const float* anch = (const float*)d_in[2];
    const float* ann  = (const float*)d_in[3];
    float* out = (float*)d_out;
    float* acc = (float*)d_ws;

    hipMemsetAsync(acc, 0, Bn * 3 * sizeof(float), stream);
    dim3 grid((An + APB - 1) / APB, Bn);
    focal_main<<<grid, 256, 0, stream>>>(cls, regr, anch, ann, acc);
    focal_final<<<1, 64, 0, stream>>>(acc, ann, out);
}

// Round 2
// 174.326 us; speedup vs baseline: 1.2021x; 1.2021x over previous
//
#include <hip/hip_runtime.h>
#include <math.h>

// Problem constants (match the JAX reference)
constexpr int Bn = 8;       // batch
constexpr int An = 120000;  // anchors
constexpr int Cn = 80;      // classes
constexpr int Mn = 32;      // max GT boxes
constexpr int APB = 256;    // anchors per block (matching kernel)
constexpr int V4 = An * Cn / 4;  // float4 elements per image (2.4M)

// d_ws layout: acc[64] floats (only [b*3+0..2] used), then status[B*A] ints
// acc: [b][0]=cls_sum, [b][1]=reg_sum, [b][2]=pos_count

// ---- Kernel 1: IoU matching + regression loss + status array -----------
__global__ __launch_bounds__(256) void focal_match(
    const float* __restrict__ regr,  // [B,A,4]
    const float* __restrict__ anch,  // [1,A,4]
    const float* __restrict__ ann,   // [B,M,5]
    int*   __restrict__ status_g,    // [B*A]
    float* __restrict__ acc)         // [64]
{
    const int b  = blockIdx.y;
    const int a0 = blockIdx.x * APB;
    const int t  = threadIdx.x;
    const int a  = a0 + t;

    __shared__ float s_ann[Mn * 5];
    if (t < Mn * 5) s_ann[t] = ann[b * Mn * 5 + t];
    __syncthreads();

    float r_sum = 0.0f;
    float p_cnt = 0.0f;
    int status = -2;

    if (a < An) {
        const float4 ab = *reinterpret_cast<const float4*>(anch + (size_t)a * 4);
        const float aw = ab.z - ab.x, ah = ab.w - ab.y;
        const float aarea = aw * ah;
        float best = -INFINITY;
        int   arg  = 0;
        #pragma unroll
        for (int m = 0; m < Mn; ++m) {
            const float bx1 = s_ann[m * 5 + 0], by1 = s_ann[m * 5 + 1];
            const float bx2 = s_ann[m * 5 + 2], by2 = s_ann[m * 5 + 3];
            float iw = fminf(ab.z, bx2) - fmaxf(ab.x, bx1);
            float ih = fminf(ab.w, by2) - fmaxf(ab.y, by1);
            iw = fmaxf(iw, 0.0f);
            ih = fmaxf(ih, 0.0f);
            const float inter = iw * ih;
            const float ua = fmaxf(aarea + (bx2 - bx1) * (by2 - by1) - inter, 1e-8f);
            const float v  = (s_ann[m * 5 + 4] != -1.0f) ? (inter / ua) : -1.0f;
            if (v > best) { best = v; arg = m; }  // strict > == first-max (jnp.argmax)
        }
        if (best >= 0.5f) {
            status = (int)s_ann[arg * 5 + 4];
            p_cnt  = 1.0f;
            const float gx1 = s_ann[arg * 5 + 0], gy1 = s_ann[arg * 5 + 1];
            const float gx2 = s_ann[arg * 5 + 2], gy2 = s_ann[arg * 5 + 3];
            float gw = gx2 - gx1, gh = gy2 - gy1;
            const float gcx = gx1 + 0.5f * gw, gcy = gy1 + 0.5f * gh; // ctr from UNclamped wh
            gw = fmaxf(gw, 1.0f);
            gh = fmaxf(gh, 1.0f);
            const float acx = ab.x + 0.5f * aw, acy = ab.y + 0.5f * ah;
            const float4 rg = *reinterpret_cast<const float4*>(regr + ((size_t)b * An + a) * 4);
            const float t0 = (gcx - acx) / aw * 10.0f;   // /0.1
            const float t1 = (gcy - acy) / ah * 10.0f;
            const float t2 = __logf(gw / aw) * 5.0f;     // /0.2
            const float t3 = __logf(gh / ah) * 5.0f;
            float d;
            d = fabsf(t0 - rg.x); r_sum += (d <= (1.0f / 9.0f)) ? 4.5f * d * d : d - (0.5f / 9.0f);
            d = fabsf(t1 - rg.y); r_sum += (d <= (1.0f / 9.0f)) ? 4.5f * d * d : d - (0.5f / 9.0f);
            d = fabsf(t2 - rg.z); r_sum += (d <= (1.0f / 9.0f)) ? 4.5f * d * d : d - (0.5f / 9.0f);
            d = fabsf(t3 - rg.w); r_sum += (d <= (1.0f / 9.0f)) ? 4.5f * d * d : d - (0.5f / 9.0f);
        } else if (best < 0.4f) {
            status = -1;  // negative
        }                 // else ignore band [0.4, 0.5)
        status_g[(size_t)b * An + a] = status;
    }

    // block reduce r_sum, p_cnt
    #pragma unroll
    for (int off = 32; off > 0; off >>= 1) {
        r_sum += __shfl_down(r_sum, off);
        p_cnt += __shfl_down(p_cnt, off);
    }
    __shared__ float s_r[4], s_p[4];
    const int wv = t >> 6;
    if ((t & 63) == 0) { s_r[wv] = r_sum; s_p[wv] = p_cnt; }
    __syncthreads();
    if (t == 0) {
        atomicAdd(&acc[b * 3 + 1], s_r[0] + s_r[1] + s_r[2] + s_r[3]);
        atomicAdd(&acc[b * 3 + 2], s_p[0] + s_p[1] + s_p[2] + s_p[3]);
    }
}

// ---- Kernel 2: focal classification loss, pure float4 stream -----------
__global__ __launch_bounds__(256) void focal_cls(
    const float* __restrict__ cls,     // [B,A,C]
    const int*   __restrict__ status_g,
    float* __restrict__ acc)
{
    const int b = blockIdx.y;
    const float4* __restrict__ base =
        reinterpret_cast<const float4*>(cls + (size_t)b * An * Cn);
    const int* __restrict__ st = status_g + (size_t)b * An;

    float sum = 0.0f;
    const int stride = gridDim.x * blockDim.x;
    for (int i = blockIdx.x * blockDim.x + threadIdx.x; i < V4; i += stride) {
        const float4 v = base[i];
        const int a  = i / 20;            // 20 float4 per 80-class row
        const int cb = (i - a * 20) * 4;  // class index of v.x
        const int s  = st[a];             // 20 consecutive lanes share -> L1 hit
        const float w = (s == -2) ? 0.0f : 1.0f;  // ignore band contributes 0

        float part = 0.0f;
        const float pv[4] = {v.x, v.y, v.z, v.w};
        #pragma unroll
        for (int k = 0; k < 4; ++k) {
            float p = fminf(fmaxf(pv[k], 1e-4f), 1.0f - 1e-4f);
            const bool tgt = (cb + k) == s;       // s>=0 only for positives
            const float q  = tgt ? p : 1.0f - p;  // prob of the correct label
            const float a_ = tgt ? 0.25f : 0.75f;
            const float om = 1.0f - q;
            part += a_ * om * om * (-__logf(q));
        }
        sum += w * part;
    }

    // block reduce + one atomic per block
    #pragma unroll
    for (int off = 32; off > 0; off >>= 1)
        sum += __shfl_down(sum, off);
    __shared__ float s_c[4];
    const int wv = threadIdx.x >> 6;
    if ((threadIdx.x & 63) == 0) s_c[wv] = sum;
    __syncthreads();
    if (threadIdx.x == 0)
        atomicAdd(&acc[b * 3 + 0], s_c[0] + s_c[1] + s_c[2] + s_c[3]);
}

// ---- Kernel 3: finalize -------------------------------------------------
__global__ void focal_final(const float* __restrict__ acc,
                            const float* __restrict__ ann,
                            float* __restrict__ out)
{
    if (threadIdx.x == 0 && blockIdx.x == 0) {
        float cm = 0.0f, rm = 0.0f;
        for (int b = 0; b < Bn; ++b) {
            int nv = 0;
            for (int m = 0; m < Mn; ++m)
                nv += (ann[b * Mn * 5 + m * 5 + 4] != -1.0f) ? 1 : 0;
            const float np  = acc[b * 3 + 2];
            const float npc = fmaxf(np, 1.0f);
            float cl = acc[b * 3 + 0] / npc;
            float rl = (np > 0.0f) ? acc[b * 3 + 1] / (npc * 4.0f) : 0.0f;
            if (nv == 0) { cl = 0.0f; rl = 0.0f; }
            cm += cl;
            rm += rl;
        }
        out[0] = cm / (float)Bn;
        out[1] = rm / (float)Bn;
    }
}

extern "C" void kernel_launch(void* const* d_in, const int* in_sizes, int n_in,
                              void* d_out, int out_size, void* d_ws, size_t ws_size,
                              hipStream_t stream) {
    const float* cls  = (const float*)d_in[0];
    const float* regr = (const float*)d_in[1];
    const float* anch = (const float*)d_in[2];
    const float* ann  = (const float*)d_in[3];
    float* out = (float*)d_out;

    float* acc      = (float*)d_ws;                 // 64 floats (256 B)
    int*   status_g = (int*)((char*)d_ws + 256);    // B*A ints = 3.84 MB

    hipMemsetAsync(acc, 0, 256, stream);

    dim3 g1((An + APB - 1) / APB, Bn);
    focal_match<<<g1, 256, 0, stream>>>(regr, anch, ann, status_g, acc);

    dim3 g2(512, Bn);  // 4096 blocks total, grid-stride over 2.4M float4/image
    focal_cls<<<g2, 256, 0, stream>>>(cls, status_g, acc);

    focal_final<<<1, 64, 0, stream>>>(acc, ann, out);
}